// Round 1
// baseline (356.469 us; speedup 1.0000x reference)
//
#include <hip/hip_runtime.h>

// Problem constants (from reference): o[N,C,D,H,W] fp32, bias[C] fp32.
#define N_  16
#define C_  32
#define D_  32
#define H_  64
#define W_  64
#define PD_ 16   // D/2
#define PH_ 32   // H/2
#define PWQ 16   // pooled-w pairs: each work item covers 4 consecutive w (2 pooled outputs)

constexpr int   ITEMS_PER_N  = C_ * PD_ * PH_ * PWQ;  // 262144
constexpr int   BLOCKS_PER_N = 128;
constexpr int   THREADS      = 256;
// out[n] = 0.5/ (PD*PH*PW) * sum(maxes) + sum(bias);  PW = 32
constexpr float SCALE = 0.5f / (float)(PD_ * PH_ * 32);

__global__ __launch_bounds__(THREADS) void pool_sum_kernel(
    const float* __restrict__ o, const float* __restrict__ bias,
    float* __restrict__ out)
{
    const int n      = blockIdx.x / BLOCKS_PER_N;
    const int blkInN = blockIdx.x % BLOCKS_PER_N;
    const float* base_n = o + (size_t)n * (C_ * D_ * H_ * W_);

    float acc = 0.0f;
    const int stride = BLOCKS_PER_N * THREADS;  // 32768
    int idx = blkInN * THREADS + threadIdx.x;

    #pragma unroll 4
    for (; idx < ITEMS_PER_N; idx += stride) {
        const int pwq = idx & 15;
        const int ph  = (idx >> 4) & 31;
        const int pd  = (idx >> 9) & 15;
        const int c   = idx >> 13;
        const float* p = base_n + (((size_t)c * D_ + 2 * pd) * H_ + 2 * ph) * W_ + 4 * pwq;
        const float4 r0 = *(const float4*)(p);                 // d,   h
        const float4 r1 = *(const float4*)(p + W_);            // d,   h+1
        const float4 r2 = *(const float4*)(p + H_ * W_);       // d+1, h
        const float4 r3 = *(const float4*)(p + H_ * W_ + W_);  // d+1, h+1
        const float m0 = fmaxf(fmaxf(fmaxf(r0.x, r0.y), fmaxf(r1.x, r1.y)),
                               fmaxf(fmaxf(r2.x, r2.y), fmaxf(r3.x, r3.y)));
        const float m1 = fmaxf(fmaxf(fmaxf(r0.z, r0.w), fmaxf(r1.z, r1.w)),
                               fmaxf(fmaxf(r2.z, r2.w), fmaxf(r3.z, r3.w)));
        acc += m0 + m1;
    }

    // Wave (64-lane) shuffle reduction, then cross-wave via LDS.
    #pragma unroll
    for (int off = 32; off > 0; off >>= 1) acc += __shfl_down(acc, off, 64);

    __shared__ float smem[THREADS / 64];
    const int wave = threadIdx.x >> 6;
    const int lane = threadIdx.x & 63;
    if (lane == 0) smem[wave] = acc;
    __syncthreads();

    if (threadIdx.x == 0) {
        float s = smem[0] + smem[1] + smem[2] + smem[3];
        s *= SCALE;
        if (blkInN == 0) {
            float bs = 0.0f;
            #pragma unroll
            for (int c = 0; c < C_; ++c) bs += bias[c];
            s += bs;
        }
        atomicAdd(&out[n], s);
    }
}

extern "C" void kernel_launch(void* const* d_in, const int* in_sizes, int n_in,
                              void* d_out, int out_size, void* d_ws, size_t ws_size,
                              hipStream_t stream) {
    const float* o    = (const float*)d_in[0];
    const float* bias = (const float*)d_in[1];
    float* out = (float*)d_out;

    // d_out is re-poisoned to 0xAA before every timed launch; zero it first.
    hipMemsetAsync(out, 0, out_size * sizeof(float), stream);

    pool_sum_kernel<<<dim3(N_ * BLOCKS_PER_N), dim3(THREADS), 0, stream>>>(o, bias, out);
}

// Round 2
// 355.191 us; speedup vs baseline: 1.0036x; 1.0036x over previous
//
#include <hip/hip_runtime.h>

// o[N,C,D,H,W] fp32 (16,32,32,64,64), bias[C] fp32.
// out[n] = SCALE * sum_{c,windows} max8(window) + sum_c bias[c]
#define N_  16
#define C_  32
#define D_  32
#define H_  64
#define W_  64

constexpr int BLOCKS_PER_N = 128;
constexpr int THREADS      = 256;
// SCALE = (1/DIVISOR) / (PD*PH*PW) = 0.5 / (16*32*32)
constexpr float SCALE = 0.5f / (float)(16 * 32 * 32);

// Stage 1: per-block partial sums of pooled maxes -> d_ws[blockIdx.x]
__global__ __launch_bounds__(THREADS) void pool_partial_kernel(
    const float* __restrict__ o, float* __restrict__ ws)
{
    const int n      = blockIdx.x / BLOCKS_PER_N;
    const int blkInN = blockIdx.x % BLOCKS_PER_N;

    // thread-in-n id in [0, 32768): decode fixed (pwq, ph, pd, c0); 8 items
    // per thread differ only by c = c0 + 4k  ->  constant 2 MiB addr stride.
    const int t   = blkInN * THREADS + threadIdx.x;
    const int pwq = t & 15;
    const int ph  = (t >> 4) & 31;
    const int pd  = (t >> 9) & 15;
    const int c0  = t >> 13;  // 0..3

    const float* p = o + (size_t)n * (C_ * D_ * H_ * W_)
                       + (((size_t)c0 * D_ + 2 * pd) * H_ + 2 * ph) * W_ + 4 * pwq;
    constexpr size_t CSTRIDE = (size_t)4 * D_ * H_ * W_;  // c += 4

    float acc = 0.0f;
    #pragma unroll
    for (int k = 0; k < 8; ++k) {
        const float* q = p + k * CSTRIDE;
        const float4 r0 = *(const float4*)(q);                 // d,   h
        const float4 r1 = *(const float4*)(q + W_);            // d,   h+1
        const float4 r2 = *(const float4*)(q + H_ * W_);       // d+1, h
        const float4 r3 = *(const float4*)(q + H_ * W_ + W_);  // d+1, h+1
        const float m0 = fmaxf(fmaxf(fmaxf(r0.x, r0.y), fmaxf(r1.x, r1.y)),
                               fmaxf(fmaxf(r2.x, r2.y), fmaxf(r3.x, r3.y)));
        const float m1 = fmaxf(fmaxf(fmaxf(r0.z, r0.w), fmaxf(r1.z, r1.w)),
                               fmaxf(fmaxf(r2.z, r2.w), fmaxf(r3.z, r3.w)));
        acc += m0 + m1;
    }

    // wave64 shuffle reduce, then cross-wave via LDS
    #pragma unroll
    for (int off = 32; off > 0; off >>= 1) acc += __shfl_down(acc, off, 64);

    __shared__ float smem[THREADS / 64];
    if ((threadIdx.x & 63) == 0) smem[threadIdx.x >> 6] = acc;
    __syncthreads();
    if (threadIdx.x == 0)
        ws[blockIdx.x] = smem[0] + smem[1] + smem[2] + smem[3];
}

// Stage 2: 16 blocks x 1 wave; reduce 128 partials per n, scale, add bias sum.
__global__ __launch_bounds__(64) void finalize_kernel(
    const float* __restrict__ ws, const float* __restrict__ bias,
    float* __restrict__ out)
{
    const int n    = blockIdx.x;
    const int lane = threadIdx.x;
    float acc = (ws[n * BLOCKS_PER_N + lane] + ws[n * BLOCKS_PER_N + 64 + lane]) * SCALE;
    if (lane < C_) acc += bias[lane];
    #pragma unroll
    for (int off = 32; off > 0; off >>= 1) acc += __shfl_down(acc, off, 64);
    if (lane == 0) out[n] = acc;
}

extern "C" void kernel_launch(void* const* d_in, const int* in_sizes, int n_in,
                              void* d_out, int out_size, void* d_ws, size_t ws_size,
                              hipStream_t stream) {
    const float* o    = (const float*)d_in[0];
    const float* bias = (const float*)d_in[1];
    float* out = (float*)d_out;
    float* ws  = (float*)d_ws;   // 2048 floats used

    pool_partial_kernel<<<dim3(N_ * BLOCKS_PER_N), dim3(THREADS), 0, stream>>>(o, ws);
    finalize_kernel<<<dim3(N_), dim3(64), 0, stream>>>(ws, bias, out);
}